// Round 1
// baseline (485.517 us; speedup 1.0000x reference)
//
#include <hip/hip_runtime.h>
#include <hip/hip_bf16.h>
#include <math.h>

#define B_   16
#define T_   4096
#define KD_  1024
#define AD_  512
#define VD_  1024

typedef float f32x4 __attribute__((ext_vector_type(4)));
typedef short s16x8 __attribute__((ext_vector_type(8)));

static __device__ __forceinline__ short f2bf(float f) {
    __hip_bfloat16 h = __float2bfloat16(f);
    return __builtin_bit_cast(short, h);
}

// ---------------- kernel 1: qb[mat][b][a] = b_bias[a] + query[b,:]·Wq[:,a] ----------------
__global__ __launch_bounds__(256) void qproj_kernel(
    const float* __restrict__ query,
    const float* __restrict__ Wq_mono, const float* __restrict__ b_mono,
    const float* __restrict__ Wq_chunk, const float* __restrict__ b_chunk,
    float* __restrict__ qb) {
    int b = blockIdx.x;       // 0..15
    int mat = blockIdx.y;     // 0..1
    const float* Wq = mat ? Wq_chunk : Wq_mono;
    const float* bb = mat ? b_chunk : b_mono;
    int a0 = threadIdx.x;     // 0..255
    const float* q = query + b * KD_;
    float s0 = 0.f, s1 = 0.f;
    for (int d = 0; d < KD_; ++d) {
        float qv = q[d];
        s0 += qv * Wq[d * AD_ + a0];
        s1 += qv * Wq[d * AD_ + a0 + 256];
    }
    qb[(mat * B_ + b) * AD_ + a0]       = s0 + bb[a0];
    qb[(mat * B_ + b) * AD_ + a0 + 256] = s1 + bb[a0 + 256];
}

// ---------------- kernel 2: WkT[n][k] (bf16) = concat(Wk_mono, Wk_chunk)[k][n] ----------------
__global__ __launch_bounds__(256) void wtrans_kernel(
    const float* __restrict__ Wk_mono, const float* __restrict__ Wk_chunk,
    short* __restrict__ WkT) {
    __shared__ float tile[32][33];
    int n0 = blockIdx.x * 32;    // combined col (0..1023)
    int k0 = blockIdx.y * 32;    // row (0..1023)
    int tx = threadIdx.x;        // 0..31
    int ty = threadIdx.y;        // 0..7
    const float* src;
    int nloc;
    if (n0 < 512) { src = Wk_mono;  nloc = n0; }
    else          { src = Wk_chunk; nloc = n0 - 512; }
#pragma unroll
    for (int i = 0; i < 4; ++i) {
        int k = ty + i * 8;
        tile[k][tx] = src[(size_t)(k0 + k) * AD_ + nloc + tx];
    }
    __syncthreads();
#pragma unroll
    for (int i = 0; i < 4; ++i) {
        int r = ty + i * 8;   // local n
        WkT[(size_t)(n0 + r) * KD_ + k0 + tx] = f2bf(tile[tx][r]);
    }
}

// ---------------- kernel 3: fused GEMM + tanh·v reduction -> e_ws ----------------
// C[m, n] over M=65536, N=1024 (n<512: mono, else chunk). 128x128 tiles, 4 waves (2x2 of 64x64).
__global__ __launch_bounds__(256) void gemm_e_kernel(
    const float* __restrict__ key,
    const short* __restrict__ WkT,
    const float* __restrict__ qb,
    const float* __restrict__ v_mono, const float* __restrict__ v_chunk,
    float* __restrict__ e_ws /* [2][B_*T_] */) {
    __shared__ short As[128][40];   // row-major [m][k], pad 40 (80B rows, 16B aligned)
    __shared__ short Bs[128][40];   // [n][k]
    int tid = threadIdx.x;
    int bid = blockIdx.x;
    int mt = bid >> 3;
    int nt = bid & 7;
    int mBase = mt * 128;
    int nBase = nt * 128;
    int lane = tid & 63;
    int wid = tid >> 6;
    int wr = wid >> 1, wc = wid & 1;
    int col16 = lane & 15, g4 = lane >> 4;

    f32x4 zero4 = {0.f, 0.f, 0.f, 0.f};
    f32x4 acc[4][4];
#pragma unroll
    for (int m = 0; m < 4; ++m)
#pragma unroll
        for (int n = 0; n < 4; ++n) acc[m][n] = zero4;

    for (int kt = 0; kt < 32; ++kt) {
        int k0 = kt * 32;
#pragma unroll
        for (int c2 = 0; c2 < 2; ++c2) {
            int c = c2 * 256 + tid;        // 512 chunks of 8 elems
            int row = c >> 2;
            int kk = (c & 3) * 8;
            // A: f32 -> bf16
            const float* srcA = key + (size_t)(mBase + row) * KD_ + k0 + kk;
            f32x4 f0 = *reinterpret_cast<const f32x4*>(srcA);
            f32x4 f1 = *reinterpret_cast<const f32x4*>(srcA + 4);
            s16x8 h;
            h[0] = f2bf(f0[0]); h[1] = f2bf(f0[1]); h[2] = f2bf(f0[2]); h[3] = f2bf(f0[3]);
            h[4] = f2bf(f1[0]); h[5] = f2bf(f1[1]); h[6] = f2bf(f1[2]); h[7] = f2bf(f1[3]);
            *reinterpret_cast<s16x8*>(&As[row][kk]) = h;
            // B: already bf16, [n][k] layout
            const short* srcB = WkT + (size_t)(nBase + row) * KD_ + k0 + kk;
            *reinterpret_cast<s16x8*>(&Bs[row][kk]) = *reinterpret_cast<const s16x8*>(srcB);
        }
        __syncthreads();
        s16x8 af[4], bfr[4];
#pragma unroll
        for (int m = 0; m < 4; ++m)
            af[m] = *reinterpret_cast<const s16x8*>(&As[wr * 64 + m * 16 + col16][g4 * 8]);
#pragma unroll
        for (int n = 0; n < 4; ++n)
            bfr[n] = *reinterpret_cast<const s16x8*>(&Bs[wc * 64 + n * 16 + col16][g4 * 8]);
#pragma unroll
        for (int m = 0; m < 4; ++m)
#pragma unroll
            for (int n = 0; n < 4; ++n)
                acc[m][n] = __builtin_amdgcn_mfma_f32_16x16x32_bf16(af[m], bfr[n], acc[m][n], 0, 0, 0);
        __syncthreads();
    }

    // epilogue: e[row] += sum_a v[a] * tanh(C[row][a] + qb[b][a])
    int bIdx = mBase >> 12;             // token row / 4096 (BM=128 divides T)
    int matrix = nBase >> 9;            // 0=mono, 1=chunk (BN=128 divides 512)
    int aBase = (nBase & 511) + wc * 64 + col16;
    const float* qbRow = qb + (matrix * B_ + bIdx) * AD_;
    const float* vv = matrix ? v_chunk : v_mono;
    float* eArr = e_ws + matrix * (B_ * T_);
    float qcol[4], vcol[4];
#pragma unroll
    for (int n = 0; n < 4; ++n) {
        int a = aBase + n * 16;
        qcol[n] = qbRow[a];
        vcol[n] = vv[a];
    }
#pragma unroll
    for (int m = 0; m < 4; ++m) {
        float s0 = 0.f, s1 = 0.f, s2 = 0.f, s3 = 0.f;
#pragma unroll
        for (int n = 0; n < 4; ++n) {
            s0 += tanhf(acc[m][n][0] + qcol[n]) * vcol[n];
            s1 += tanhf(acc[m][n][1] + qcol[n]) * vcol[n];
            s2 += tanhf(acc[m][n][2] + qcol[n]) * vcol[n];
            s3 += tanhf(acc[m][n][3] + qcol[n]) * vcol[n];
        }
#pragma unroll
        for (int mask = 1; mask < 16; mask <<= 1) {
            s0 += __shfl_xor(s0, mask, 64);
            s1 += __shfl_xor(s1, mask, 64);
            s2 += __shfl_xor(s2, mask, 64);
            s3 += __shfl_xor(s3, mask, 64);
        }
        if (col16 == 0) {
            int rowB = mBase + wr * 64 + m * 16 + g4 * 4;
            atomicAdd(&eArr[rowB + 0], s0);
            atomicAdd(&eArr[rowB + 1], s1);
            atomicAdd(&eArr[rowB + 2], s2);
            atomicAdd(&eArr[rowB + 3], s3);
        }
    }
}

// ---------------- kernel 4: per-batch scan -> aw, beta ----------------
__global__ __launch_bounds__(256) void scan_kernel(
    const float* __restrict__ e_ws,
    const float* __restrict__ noise,
    const float* __restrict__ r_mono, const float* __restrict__ r_chunk,
    float* __restrict__ aw_out, float* __restrict__ beta_out) {
    __shared__ float s_aw[T_];
    __shared__ float s_sexp[T_];
    __shared__ float s_ad[T_];
    __shared__ float s_part[256];
    __shared__ float s_scal;
    int b = blockIdx.x;
    int tid = threadIdx.x;
    int t0 = tid * 16;
    const float* em = e_ws + b * T_;
    const float* ec = e_ws + B_ * T_ + b * T_;
    const float* nz = noise + b * T_;
    float rm = r_mono[0], rc = r_chunk[0];

    // monotonic: p = sigmoid(e+r+noise); aw = p * exp(1 + exclusive_cumsum(log(clip(1-p,1e-10,1))))
    float pv[16], lp[16];
    float run = 0.f;
#pragma unroll
    for (int j = 0; j < 16; ++j) {
        float x = em[t0 + j] + rm + nz[t0 + j];
        float p = 1.f / (1.f + expf(-x));
        pv[j] = p;
        float om = fminf(fmaxf(1.f - p, 1e-10f), 1.f);
        float lg = logf(om);
        lp[j] = run;   // local exclusive prefix
        run += lg;
    }
    s_part[tid] = run;
    __syncthreads();
    if (tid == 0) {
        float a = 0.f;
        for (int i = 0; i < 256; ++i) { float t = s_part[i]; s_part[i] = a; a += t; }
    }
    __syncthreads();
    float base = 1.f + s_part[tid];
#pragma unroll
    for (int j = 0; j < 16; ++j) {
        float aw = pv[j] * expf(base + lp[j]);
        s_aw[t0 + j] = aw;
        aw_out[b * T_ + t0 + j] = aw;
    }
    // chunk: softmax_exp with global max, then windowed sums
    float evs[16];
    float lmax = -INFINITY;
#pragma unroll
    for (int j = 0; j < 16; ++j) {
        float x = ec[t0 + j] + rc;
        evs[j] = x;
        lmax = fmaxf(lmax, x);
    }
    s_part[tid] = lmax;
    __syncthreads();
    if (tid == 0) {
        float mx = s_part[0];
        for (int i = 1; i < 256; ++i) mx = fmaxf(mx, s_part[i]);
        s_scal = mx;
    }
    __syncthreads();
    float mx = s_scal;
#pragma unroll
    for (int j = 0; j < 16; ++j)
        s_sexp[t0 + j] = fmaxf(expf(evs[j] - mx), 1e-5f);
    __syncthreads();
#pragma unroll
    for (int j = 0; j < 16; ++j) {
        int t = t0 + j;
        int lo = t - 7; if (lo < 0) lo = 0;
        float d = 0.f;
        for (int i = lo; i <= t; ++i) d += s_sexp[i];
        s_ad[t] = s_aw[t] / d;
    }
    __syncthreads();
#pragma unroll
    for (int j = 0; j < 16; ++j) {
        int t = t0 + j;
        int hi = t + 7; if (hi > T_ - 1) hi = T_ - 1;
        float m2 = 0.f;
        for (int i = t; i <= hi; ++i) m2 += s_ad[i];
        beta_out[b * T_ + t] = s_sexp[t] * m2;
    }
}

// ---------------- kernel 5: cv[b][d] = sum_t beta[b][t]*value[b][t][d] ----------------
__global__ __launch_bounds__(256) void cv_kernel(
    const float* __restrict__ value,
    const float* __restrict__ beta,
    float* __restrict__ cv) {
    __shared__ float s_beta[128];
    int b = blockIdx.x;
    int tc = blockIdx.y;
    int tid = threadIdx.x;
    int t0 = tc * 128;
    if (tid < 128) s_beta[tid] = beta[b * T_ + t0 + tid];
    __syncthreads();
    int d0 = tid * 4;
    f32x4 acc = {0.f, 0.f, 0.f, 0.f};
    const float* vp = value + (size_t)(b * T_ + t0) * VD_ + d0;
#pragma unroll 4
    for (int i = 0; i < 128; ++i) {
        f32x4 v = *reinterpret_cast<const f32x4*>(vp + (size_t)i * VD_);
        float bt = s_beta[i];
        acc[0] += bt * v[0];
        acc[1] += bt * v[1];
        acc[2] += bt * v[2];
        acc[3] += bt * v[3];
    }
    atomicAdd(&cv[b * VD_ + d0 + 0], acc[0]);
    atomicAdd(&cv[b * VD_ + d0 + 1], acc[1]);
    atomicAdd(&cv[b * VD_ + d0 + 2], acc[2]);
    atomicAdd(&cv[b * VD_ + d0 + 3], acc[3]);
}

extern "C" void kernel_launch(void* const* d_in, const int* in_sizes, int n_in,
                              void* d_out, int out_size, void* d_ws, size_t ws_size,
                              hipStream_t stream) {
    const float* key      = (const float*)d_in[0];
    const float* value    = (const float*)d_in[1];
    const float* query    = (const float*)d_in[2];
    const float* noise    = (const float*)d_in[3];
    const float* Wk_mono  = (const float*)d_in[4];
    const float* b_mono   = (const float*)d_in[5];
    const float* Wq_mono  = (const float*)d_in[6];
    const float* Wk_chunk = (const float*)d_in[7];
    const float* b_chunk  = (const float*)d_in[8];
    const float* Wq_chunk = (const float*)d_in[9];
    const float* r_mono   = (const float*)d_in[10];
    const float* r_chunk  = (const float*)d_in[11];
    const float* v_mono   = (const float*)d_in[12];
    const float* v_chunk  = (const float*)d_in[13];
    float* out = (float*)d_out;   // [0,16384): cv ; [16384, 81920): aw

    char* ws = (char*)d_ws;
    float* e_ws = (float*)ws;                                     // 2*65536 f32 = 512 KB
    float* qb   = (float*)(ws + 2 * B_ * T_ * 4);                 // 16384 f32 = 64 KB
    short* WkT  = (short*)(ws + 2 * B_ * T_ * 4 + 16384 * 4);     // 1024*1024 bf16 = 2 MB
    float* beta = (float*)(ws + 2 * B_ * T_ * 4 + 16384 * 4 + 1024 * 1024 * 2); // 256 KB

    hipMemsetAsync(e_ws, 0, 2 * B_ * T_ * sizeof(float), stream);
    hipMemsetAsync(out, 0, B_ * VD_ * sizeof(float), stream);

    qproj_kernel<<<dim3(16, 2), 256, 0, stream>>>(query, Wq_mono, b_mono, Wq_chunk, b_chunk, qb);
    wtrans_kernel<<<dim3(32, 32), dim3(32, 8), 0, stream>>>(Wk_mono, Wk_chunk, WkT);
    gemm_e_kernel<<<4096, 256, 0, stream>>>(key, WkT, qb, v_mono, v_chunk, e_ws);
    scan_kernel<<<16, 256, 0, stream>>>(e_ws, noise, r_mono, r_chunk, out + B_ * VD_, beta);
    cv_kernel<<<dim3(16, 32), 256, 0, stream>>>(value, beta, out);
}

// Round 2
// 436.386 us; speedup vs baseline: 1.1126x; 1.1126x over previous
//
#include <hip/hip_runtime.h>
#include <hip/hip_bf16.h>
#include <math.h>

#define B_   16
#define T_   4096
#define KD_  1024
#define AD_  512
#define VD_  1024

typedef float f32x4 __attribute__((ext_vector_type(4)));
typedef short s16x8 __attribute__((ext_vector_type(8)));

static __device__ __forceinline__ short f2bf(float f) {
    __hip_bfloat16 h = __float2bfloat16(f);
    return __builtin_bit_cast(short, h);
}

static __device__ __forceinline__ void gload16(const void* g, void* l) {
    __builtin_amdgcn_global_load_lds(
        (const __attribute__((address_space(1))) void*)(g),
        (__attribute__((address_space(3))) void*)(l), 16, 0, 0);
}

// ---------------- kernel 0: key f32 -> bf16 ----------------
__global__ __launch_bounds__(256) void cvt_key_kernel(
    const float* __restrict__ key, short* __restrict__ out) {
    const size_t nchunk = (size_t)B_ * T_ * KD_ / 8;
    size_t stride = (size_t)gridDim.x * 256;
    for (size_t idx = (size_t)blockIdx.x * 256 + threadIdx.x; idx < nchunk; idx += stride) {
        const float* p = key + idx * 8;
        f32x4 f0 = *reinterpret_cast<const f32x4*>(p);
        f32x4 f1 = *reinterpret_cast<const f32x4*>(p + 4);
        s16x8 h;
        h[0] = f2bf(f0[0]); h[1] = f2bf(f0[1]); h[2] = f2bf(f0[2]); h[3] = f2bf(f0[3]);
        h[4] = f2bf(f1[0]); h[5] = f2bf(f1[1]); h[6] = f2bf(f1[2]); h[7] = f2bf(f1[3]);
        *reinterpret_cast<s16x8*>(out + idx * 8) = h;
    }
}

// ---------------- kernel 1: qb[mat][b][a] = b_bias[a] + query[b,:]·Wq[:,a] ----------------
__global__ __launch_bounds__(256) void qproj_kernel(
    const float* __restrict__ query,
    const float* __restrict__ Wq_mono, const float* __restrict__ b_mono,
    const float* __restrict__ Wq_chunk, const float* __restrict__ b_chunk,
    float* __restrict__ qb) {
    int b = blockIdx.x;       // 0..15
    int mat = blockIdx.y;     // 0..1
    const float* Wq = mat ? Wq_chunk : Wq_mono;
    const float* bb = mat ? b_chunk : b_mono;
    int a0 = threadIdx.x;     // 0..255
    const float* q = query + b * KD_;
    float s0 = 0.f, s1 = 0.f;
    for (int d = 0; d < KD_; ++d) {
        float qv = q[d];
        s0 += qv * Wq[d * AD_ + a0];
        s1 += qv * Wq[d * AD_ + a0 + 256];
    }
    qb[(mat * B_ + b) * AD_ + a0]       = s0 + bb[a0];
    qb[(mat * B_ + b) * AD_ + a0 + 256] = s1 + bb[a0 + 256];
}

// ---------------- kernel 2: WkT[n][k] (bf16) = concat(Wk_mono, Wk_chunk)[k][n] ----------------
__global__ __launch_bounds__(256) void wtrans_kernel(
    const float* __restrict__ Wk_mono, const float* __restrict__ Wk_chunk,
    short* __restrict__ WkT) {
    __shared__ float tile[32][33];
    int n0 = blockIdx.x * 32;    // combined col (0..1023)
    int k0 = blockIdx.y * 32;    // row (0..1023)
    int tx = threadIdx.x;        // 0..31
    int ty = threadIdx.y;        // 0..7
    const float* src;
    int nloc;
    if (n0 < 512) { src = Wk_mono;  nloc = n0; }
    else          { src = Wk_chunk; nloc = n0 - 512; }
#pragma unroll
    for (int i = 0; i < 4; ++i) {
        int k = ty + i * 8;
        tile[k][tx] = src[(size_t)(k0 + k) * AD_ + nloc + tx];
    }
    __syncthreads();
#pragma unroll
    for (int i = 0; i < 4; ++i) {
        int r = ty + i * 8;   // local n
        WkT[(size_t)(n0 + r) * KD_ + k0 + tx] = f2bf(tile[tx][r]);
    }
}

// ---------------- kernel 3: fused GEMM (bf16 A via global_load_lds) + tanh·v -> e_ws ----------------
// m97 structure: 128x128 tile, BK=32, linear LDS, global_load_lds width=16, 2 barriers/K-step.
__global__ __launch_bounds__(256) void gemm_e_bf_kernel(
    const short* __restrict__ key_bf,
    const short* __restrict__ WkT,
    const float* __restrict__ qb,
    const float* __restrict__ v_mono, const float* __restrict__ v_chunk,
    float* __restrict__ e_ws /* [2][B_*T_] */) {
    __shared__ short As[128 * 32];   // linear [row][k], row-stride 32 (required by global_load_lds)
    __shared__ short Bs[128 * 32];   // [n][k]
    int tid = threadIdx.x;
    int bid = blockIdx.x;
    int mt = bid >> 3;
    int nt = bid & 7;
    int mBase = mt * 128;
    int nBase = nt * 128;
    int lane = tid & 63;
    int wid = tid >> 6;
    int wr = wid >> 1, wc = wid & 1;
    int col16 = lane & 15, g4 = lane >> 4;

    // staging chunk ids: chunk c covers LDS bytes [c*16, c*16+16) = row c>>2, k (c&3)*8
    int c0 = wid * 128 + lane;     // issue 0
    int c1 = c0 + 64;              // issue 1
    const short* pA0 = key_bf + (size_t)(mBase + (c0 >> 2)) * KD_ + (c0 & 3) * 8;
    const short* pA1 = key_bf + (size_t)(mBase + (c1 >> 2)) * KD_ + (c1 & 3) * 8;
    const short* pB0 = WkT + (size_t)(nBase + (c0 >> 2)) * KD_ + (c0 & 3) * 8;
    const short* pB1 = WkT + (size_t)(nBase + (c1 >> 2)) * KD_ + (c1 & 3) * 8;
    short* sA0 = &As[(wid * 128 + 0) * 8];   // wave-uniform LDS dests (8 shorts = 16B per chunk)
    short* sA1 = &As[(wid * 128 + 64) * 8];
    short* sB0 = &Bs[(wid * 128 + 0) * 8];
    short* sB1 = &Bs[(wid * 128 + 64) * 8];

    f32x4 zero4 = {0.f, 0.f, 0.f, 0.f};
    f32x4 acc[4][4];
#pragma unroll
    for (int m = 0; m < 4; ++m)
#pragma unroll
        for (int n = 0; n < 4; ++n) acc[m][n] = zero4;

    for (int kt = 0; kt < 32; ++kt) {
        gload16(pA0, sA0);
        gload16(pA1, sA1);
        gload16(pB0, sB0);
        gload16(pB1, sB1);
        __syncthreads();   // compiler emits vmcnt(0) drain before barrier
        s16x8 af[4], bfr[4];
#pragma unroll
        for (int m = 0; m < 4; ++m)
            af[m] = *reinterpret_cast<const s16x8*>(&As[(wr * 64 + m * 16 + col16) * 32 + g4 * 8]);
#pragma unroll
        for (int n = 0; n < 4; ++n)
            bfr[n] = *reinterpret_cast<const s16x8*>(&Bs[(wc * 64 + n * 16 + col16) * 32 + g4 * 8]);
#pragma unroll
        for (int m = 0; m < 4; ++m)
#pragma unroll
            for (int n = 0; n < 4; ++n)
                acc[m][n] = __builtin_amdgcn_mfma_f32_16x16x32_bf16(af[m], bfr[n], acc[m][n], 0, 0, 0);
        __syncthreads();
        pA0 += 32; pA1 += 32; pB0 += 32; pB1 += 32;
    }

    // epilogue: e[row] += sum_a v[a] * tanh(C[row][a] + qb[b][a])
    int bIdx = mBase >> 12;             // token row / 4096 (BM=128 divides T)
    int matrix = nBase >> 9;            // 0=mono, 1=chunk
    int aBase = (nBase & 511) + wc * 64 + col16;
    const float* qbRow = qb + (matrix * B_ + bIdx) * AD_;
    const float* vv = matrix ? v_chunk : v_mono;
    float* eArr = e_ws + matrix * (B_ * T_);
    float qcol[4], vcol[4];
#pragma unroll
    for (int n = 0; n < 4; ++n) {
        int a = aBase + n * 16;
        qcol[n] = qbRow[a];
        vcol[n] = vv[a];
    }
#pragma unroll
    for (int m = 0; m < 4; ++m) {
        float s0 = 0.f, s1 = 0.f, s2 = 0.f, s3 = 0.f;
#pragma unroll
        for (int n = 0; n < 4; ++n) {
            s0 += tanhf(acc[m][n][0] + qcol[n]) * vcol[n];
            s1 += tanhf(acc[m][n][1] + qcol[n]) * vcol[n];
            s2 += tanhf(acc[m][n][2] + qcol[n]) * vcol[n];
            s3 += tanhf(acc[m][n][3] + qcol[n]) * vcol[n];
        }
#pragma unroll
        for (int mask = 1; mask < 16; mask <<= 1) {
            s0 += __shfl_xor(s0, mask, 64);
            s1 += __shfl_xor(s1, mask, 64);
            s2 += __shfl_xor(s2, mask, 64);
            s3 += __shfl_xor(s3, mask, 64);
        }
        if (col16 == 0) {
            int rowB = mBase + wr * 64 + m * 16 + g4 * 4;
            atomicAdd(&eArr[rowB + 0], s0);
            atomicAdd(&eArr[rowB + 1], s1);
            atomicAdd(&eArr[rowB + 2], s2);
            atomicAdd(&eArr[rowB + 3], s3);
        }
    }
}

// ---------------- fallback GEMM (round-1, f32 A converted in-kernel) ----------------
__global__ __launch_bounds__(256) void gemm_e_f32a_kernel(
    const float* __restrict__ key,
    const short* __restrict__ WkT,
    const float* __restrict__ qb,
    const float* __restrict__ v_mono, const float* __restrict__ v_chunk,
    float* __restrict__ e_ws) {
    __shared__ short As[128][40];
    __shared__ short Bs[128][40];
    int tid = threadIdx.x;
    int bid = blockIdx.x;
    int mt = bid >> 3;
    int nt = bid & 7;
    int mBase = mt * 128;
    int nBase = nt * 128;
    int lane = tid & 63;
    int wid = tid >> 6;
    int wr = wid >> 1, wc = wid & 1;
    int col16 = lane & 15, g4 = lane >> 4;

    f32x4 zero4 = {0.f, 0.f, 0.f, 0.f};
    f32x4 acc[4][4];
#pragma unroll
    for (int m = 0; m < 4; ++m)
#pragma unroll
        for (int n = 0; n < 4; ++n) acc[m][n] = zero4;

    for (int kt = 0; kt < 32; ++kt) {
        int k0 = kt * 32;
#pragma unroll
        for (int c2 = 0; c2 < 2; ++c2) {
            int c = c2 * 256 + tid;
            int row = c >> 2;
            int kk = (c & 3) * 8;
            const float* srcA = key + (size_t)(mBase + row) * KD_ + k0 + kk;
            f32x4 f0 = *reinterpret_cast<const f32x4*>(srcA);
            f32x4 f1 = *reinterpret_cast<const f32x4*>(srcA + 4);
            s16x8 h;
            h[0] = f2bf(f0[0]); h[1] = f2bf(f0[1]); h[2] = f2bf(f0[2]); h[3] = f2bf(f0[3]);
            h[4] = f2bf(f1[0]); h[5] = f2bf(f1[1]); h[6] = f2bf(f1[2]); h[7] = f2bf(f1[3]);
            *reinterpret_cast<s16x8*>(&As[row][kk]) = h;
            const short* srcB = WkT + (size_t)(nBase + row) * KD_ + k0 + kk;
            *reinterpret_cast<s16x8*>(&Bs[row][kk]) = *reinterpret_cast<const s16x8*>(srcB);
        }
        __syncthreads();
        s16x8 af[4], bfr[4];
#pragma unroll
        for (int m = 0; m < 4; ++m)
            af[m] = *reinterpret_cast<const s16x8*>(&As[wr * 64 + m * 16 + col16][g4 * 8]);
#pragma unroll
        for (int n = 0; n < 4; ++n)
            bfr[n] = *reinterpret_cast<const s16x8*>(&Bs[wc * 64 + n * 16 + col16][g4 * 8]);
#pragma unroll
        for (int m = 0; m < 4; ++m)
#pragma unroll
            for (int n = 0; n < 4; ++n)
                acc[m][n] = __builtin_amdgcn_mfma_f32_16x16x32_bf16(af[m], bfr[n], acc[m][n], 0, 0, 0);
        __syncthreads();
    }

    int bIdx = mBase >> 12;
    int matrix = nBase >> 9;
    int aBase = (nBase & 511) + wc * 64 + col16;
    const float* qbRow = qb + (matrix * B_ + bIdx) * AD_;
    const float* vv = matrix ? v_chunk : v_mono;
    float* eArr = e_ws + matrix * (B_ * T_);
    float qcol[4], vcol[4];
#pragma unroll
    for (int n = 0; n < 4; ++n) {
        int a = aBase + n * 16;
        qcol[n] = qbRow[a];
        vcol[n] = vv[a];
    }
#pragma unroll
    for (int m = 0; m < 4; ++m) {
        float s0 = 0.f, s1 = 0.f, s2 = 0.f, s3 = 0.f;
#pragma unroll
        for (int n = 0; n < 4; ++n) {
            s0 += tanhf(acc[m][n][0] + qcol[n]) * vcol[n];
            s1 += tanhf(acc[m][n][1] + qcol[n]) * vcol[n];
            s2 += tanhf(acc[m][n][2] + qcol[n]) * vcol[n];
            s3 += tanhf(acc[m][n][3] + qcol[n]) * vcol[n];
        }
#pragma unroll
        for (int mask = 1; mask < 16; mask <<= 1) {
            s0 += __shfl_xor(s0, mask, 64);
            s1 += __shfl_xor(s1, mask, 64);
            s2 += __shfl_xor(s2, mask, 64);
            s3 += __shfl_xor(s3, mask, 64);
        }
        if (col16 == 0) {
            int rowB = mBase + wr * 64 + m * 16 + g4 * 4;
            atomicAdd(&eArr[rowB + 0], s0);
            atomicAdd(&eArr[rowB + 1], s1);
            atomicAdd(&eArr[rowB + 2], s2);
            atomicAdd(&eArr[rowB + 3], s3);
        }
    }
}

// ---------------- kernel 4: per-batch scan -> aw, beta ----------------
__global__ __launch_bounds__(256) void scan_kernel(
    const float* __restrict__ e_ws,
    const float* __restrict__ noise,
    const float* __restrict__ r_mono, const float* __restrict__ r_chunk,
    float* __restrict__ aw_out, float* __restrict__ beta_out) {
    __shared__ float s_aw[T_];
    __shared__ float s_sexp[T_];
    __shared__ float s_ad[T_];
    __shared__ float s_w[4];
    int b = blockIdx.x;
    int tid = threadIdx.x;
    int lane = tid & 63;
    int wid4 = tid >> 6;
    int t0 = tid * 16;
    const float* em = e_ws + b * T_;
    const float* ec = e_ws + B_ * T_ + b * T_;
    const float* nz = noise + b * T_;
    float rm = r_mono[0], rc = r_chunk[0];

    // monotonic: p = sigmoid(e+r+noise); aw = p * exp(1 + exclusive_cumsum(log(clip(1-p,1e-10,1))))
    float pv[16], lp[16];
    float run = 0.f;
#pragma unroll
    for (int j = 0; j < 16; ++j) {
        float x = em[t0 + j] + rm + nz[t0 + j];
        float p = 1.f / (1.f + expf(-x));
        pv[j] = p;
        float om = fminf(fmaxf(1.f - p, 1e-10f), 1.f);
        lp[j] = run;   // local exclusive prefix
        run += logf(om);
    }
    // block-level exclusive scan of per-thread sums: wave shfl_up scan + cross-wave combine
    float x = run;
#pragma unroll
    for (int off = 1; off < 64; off <<= 1) {
        float y = __shfl_up(x, off, 64);
        if (lane >= off) x += y;
    }
    if (lane == 63) s_w[wid4] = x;
    __syncthreads();
    float wbase = 0.f;
#pragma unroll
    for (int i = 0; i < 3; ++i) if (i < wid4) wbase += s_w[i];
    float base = 1.f + (wbase + x - run);   // exclusive prefix of `run` across block
#pragma unroll
    for (int j = 0; j < 16; ++j) {
        float aw = pv[j] * expf(base + lp[j]);
        s_aw[t0 + j] = aw;
        aw_out[b * T_ + t0 + j] = aw;
    }
    // chunk: softmax_exp with global max, then windowed sums
    float evs[16];
    float lmax = -INFINITY;
#pragma unroll
    for (int j = 0; j < 16; ++j) {
        float v = ec[t0 + j] + rc;
        evs[j] = v;
        lmax = fmaxf(lmax, v);
    }
#pragma unroll
    for (int off = 1; off < 64; off <<= 1)
        lmax = fmaxf(lmax, __shfl_xor(lmax, off, 64));
    __syncthreads();   // s_w reuse guard
    if (lane == 0) s_w[wid4] = lmax;
    __syncthreads();
    float mx = fmaxf(fmaxf(s_w[0], s_w[1]), fmaxf(s_w[2], s_w[3]));
#pragma unroll
    for (int j = 0; j < 16; ++j)
        s_sexp[t0 + j] = fmaxf(expf(evs[j] - mx), 1e-5f);
    __syncthreads();
#pragma unroll
    for (int j = 0; j < 16; ++j) {
        int t = t0 + j;
        int lo = t - 7; if (lo < 0) lo = 0;
        float d = 0.f;
        for (int i = lo; i <= t; ++i) d += s_sexp[i];
        s_ad[t] = s_aw[t] / d;
    }
    __syncthreads();
#pragma unroll
    for (int j = 0; j < 16; ++j) {
        int t = t0 + j;
        int hi = t + 7; if (hi > T_ - 1) hi = T_ - 1;
        float m2 = 0.f;
        for (int i = t; i <= hi; ++i) m2 += s_ad[i];
        beta_out[b * T_ + t] = s_sexp[t] * m2;
    }
}

// ---------------- kernel 5: cv[b][d] = sum_t beta[b][t]*value[b][t][d] ----------------
__global__ __launch_bounds__(256) void cv_kernel(
    const float* __restrict__ value,
    const float* __restrict__ beta,
    float* __restrict__ cv) {
    __shared__ float s_beta[128];
    int b = blockIdx.x;
    int tc = blockIdx.y;
    int tid = threadIdx.x;
    int t0 = tc * 128;
    if (tid < 128) s_beta[tid] = beta[b * T_ + t0 + tid];
    __syncthreads();
    int d0 = tid * 4;
    f32x4 acc = {0.f, 0.f, 0.f, 0.f};
    const float* vp = value + (size_t)(b * T_ + t0) * VD_ + d0;
#pragma unroll 4
    for (int i = 0; i < 128; ++i) {
        f32x4 v = *reinterpret_cast<const f32x4*>(vp + (size_t)i * VD_);
        float bt = s_beta[i];
        acc[0] += bt * v[0];
        acc[1] += bt * v[1];
        acc[2] += bt * v[2];
        acc[3] += bt * v[3];
    }
    atomicAdd(&cv[b * VD_ + d0 + 0], acc[0]);
    atomicAdd(&cv[b * VD_ + d0 + 1], acc[1]);
    atomicAdd(&cv[b * VD_ + d0 + 2], acc[2]);
    atomicAdd(&cv[b * VD_ + d0 + 3], acc[3]);
}

extern "C" void kernel_launch(void* const* d_in, const int* in_sizes, int n_in,
                              void* d_out, int out_size, void* d_ws, size_t ws_size,
                              hipStream_t stream) {
    const float* key      = (const float*)d_in[0];
    const float* value    = (const float*)d_in[1];
    const float* query    = (const float*)d_in[2];
    const float* noise    = (const float*)d_in[3];
    const float* Wk_mono  = (const float*)d_in[4];
    const float* b_mono   = (const float*)d_in[5];
    const float* Wq_mono  = (const float*)d_in[6];
    const float* Wk_chunk = (const float*)d_in[7];
    const float* b_chunk  = (const float*)d_in[8];
    const float* Wq_chunk = (const float*)d_in[9];
    const float* r_mono   = (const float*)d_in[10];
    const float* r_chunk  = (const float*)d_in[11];
    const float* v_mono   = (const float*)d_in[12];
    const float* v_chunk  = (const float*)d_in[13];
    float* out = (float*)d_out;   // [0,16384): cv ; [16384, 81920): aw

    char* ws = (char*)d_ws;
    size_t off = 0;
    float* e_ws = (float*)(ws + off); off += 2 * B_ * T_ * sizeof(float);      // 512 KB
    float* qb   = (float*)(ws + off); off += 2 * B_ * AD_ * sizeof(float);     // 64 KB
    short* WkT  = (short*)(ws + off); off += (size_t)KD_ * KD_ * 2;            // 2 MB
    float* beta = (float*)(ws + off); off += B_ * T_ * sizeof(float);          // 256 KB
    size_t key_bf_off = off;
    size_t key_bf_bytes = (size_t)B_ * T_ * KD_ * 2;                           // 134 MB
    bool big_ws = (ws_size >= key_bf_off + key_bf_bytes);
    short* key_bf = (short*)(ws + key_bf_off);

    hipMemsetAsync(e_ws, 0, 2 * B_ * T_ * sizeof(float), stream);
    hipMemsetAsync(out, 0, B_ * VD_ * sizeof(float), stream);

    qproj_kernel<<<dim3(16, 2), 256, 0, stream>>>(query, Wq_mono, b_mono, Wq_chunk, b_chunk, qb);
    wtrans_kernel<<<dim3(32, 32), dim3(32, 8), 0, stream>>>(Wk_mono, Wk_chunk, WkT);
    if (big_ws) {
        cvt_key_kernel<<<4096, 256, 0, stream>>>(key, key_bf);
        gemm_e_bf_kernel<<<4096, 256, 0, stream>>>(key_bf, WkT, qb, v_mono, v_chunk, e_ws);
    } else {
        gemm_e_f32a_kernel<<<4096, 256, 0, stream>>>(key, WkT, qb, v_mono, v_chunk, e_ws);
    }
    scan_kernel<<<16, 256, 0, stream>>>(e_ws, noise, r_mono, r_chunk, out + B_ * VD_, beta);
    cv_kernel<<<dim3(16, 32), 256, 0, stream>>>(value, beta, out);
}